// Round 10
// baseline (137.635 us; speedup 1.0000x reference)
//
#include <hip/hip_runtime.h>
#include <hip/hip_bf16.h>
#include <math.h>

// ---------------------------------------------------------------------------
// HybridClassifier, split pipeline:
//   K0: w1 -> bf16 [128][800] (zero-padded)
//   K1 qfilter: 1 wave = 64 (batch,patch) items, grid 6272x256, no barriers.
//       trig -> psi (wave-private LDS) -> phi^T = U*psi^T (16x16x16 MFMA)
//       -> square+pack -> meas = Z*q (2nd MFMA) -> feats bf16 global.
//   K2 tail: 512 threads/block, 16 batch rows; feats rows staged in LDS;
//       fc1 via MFMA (1 wave = 16 cols), launch_bounds(512,1) so the compiler
//       can pipeline the K-loop loads; dual accumulators break the MFMA
//       dependency chain -> fc2+relu -> fc3 -> analytic head -> out.
// ---------------------------------------------------------------------------

#define BATCH   8192
#define NPATCH  196
#define KPAD    800
#define FLD2    808     // feats LDS row stride (halves), <=2-way banks
#define H1LD    132
#define NCHUNKS ((BATCH * NPATCH) / 64)   // 25088 exact

typedef __attribute__((ext_vector_type(8))) short bfrag;    // 8 bf16 (x32 MFMA)
typedef __attribute__((ext_vector_type(4))) short bfrag4;   // 4 bf16 (x16 MFMA)
typedef __attribute__((ext_vector_type(4))) float f32x4;

#if __has_builtin(__builtin_amdgcn_mfma_f32_16x16x16bf16_1k)
#define USE_X16 1
#else
#define USE_X16 0
#endif

static __device__ __forceinline__ unsigned short f2bf(float f) {
    __hip_bfloat16 h = __float2bfloat16(f);
    return __builtin_bit_cast(unsigned short, h);
}
static __device__ __forceinline__ unsigned int pkbf(float lo, float hi) {
    return ((unsigned int)f2bf(hi) << 16) | (unsigned int)f2bf(lo);
}

// ===========================================================================
// K0: w1 (fp32 [120][784]) -> bf16 [128][800], zero-padded.
// ===========================================================================
__global__ __launch_bounds__(256) void w1prep_kernel(
    const float* __restrict__ w1, unsigned short* __restrict__ w1B)
{
    int t = blockIdx.x * 256 + threadIdx.x;
    if (t >= 128 * KPAD) return;
    int n = t / KPAD;
    int k = t - n * KPAD;
    float v = (n < 120 && k < 784) ? w1[n * 784 + k] : 0.f;
    w1B[t] = f2bf(v);
}

// ===========================================================================
// K1: quantum filter. One chunk (64 items) per wave, no loops, no barriers.
// Grid 6272 x 256 (= 25088 waves = all chunks exactly).
// ===========================================================================
__global__ __launch_bounds__(256) void qfilter_kernel(
    const float* __restrict__ x, const float* __restrict__ U,
    unsigned short* __restrict__ featsB)
{
    __shared__ __align__(16) unsigned short psiL[4][64][16];   // 8192 B

    const int lane = threadIdx.x & 63;
    const int wv   = threadIdx.x >> 6;
    const int lrow = lane & 15;
    const int lgrp = lane >> 4;
    const int base = (blockIdx.x * 4 + wv) * 64;

#if USE_X16
    // U as 16x16x16 A-frag: A[row=lrow][k=4*lgrp+j], 2 VGPR
    bfrag4 Uf16;
    {
        union { bfrag4 f; unsigned int u[2]; } uu;
        float4 a = *reinterpret_cast<const float4*>(U + lrow * 16 + lgrp * 4);
        uu.u[0] = pkbf(a.x, a.y);
        uu.u[1] = pkbf(a.z, a.w);
        Uf16 = uu.f;
    }
    // PauliZ sign matrix A-frag: A[row=w][k=i] = 1-2*bit_{3-w}(i), rows>=4: 0
    bfrag4 Zf;
    {
        union { bfrag4 f; unsigned int u[2]; } zz;
        if (lrow < 4) {
            float z[4];
#pragma unroll
            for (int j = 0; j < 4; ++j) {
                int k = 4 * lgrp + j;
                z[j] = ((k >> (3 - lrow)) & 1) ? -1.f : 1.f;
            }
            zz.u[0] = pkbf(z[0], z[1]);
            zz.u[1] = pkbf(z[2], z[3]);
        } else {
            zz.u[0] = zz.u[1] = 0u;
        }
        Zf = zz.f;
    }
#else
    bfrag Uf;
    {
        union { bfrag f; unsigned int u[4]; } uu;
        if (lgrp < 2) {
            float4 a = *reinterpret_cast<const float4*>(U + lrow * 16 + lgrp * 8);
            float4 b = *reinterpret_cast<const float4*>(U + lrow * 16 + lgrp * 8 + 4);
            uu.u[0] = pkbf(a.x, a.y); uu.u[1] = pkbf(a.z, a.w);
            uu.u[2] = pkbf(b.x, b.y); uu.u[3] = pkbf(b.z, b.w);
        } else {
            uu.u[0] = uu.u[1] = uu.u[2] = uu.u[3] = 0u;
        }
        Uf = uu.f;
    }
#endif

    // ---- per-lane item: trig -> psi -> LDS (wave-private, no barrier) ----
    {
        int item = base + lane;
        int b  = item / NPATCH;
        int p  = item - b * NPATCH;
        int pr = p / 14;
        int pc = p - pr * 14;
        const float* xr = x + (size_t)b * 784 + pr * 56 + pc * 2;
        float2 xa = *reinterpret_cast<const float2*>(xr);
        float2 xb = *reinterpret_cast<const float2*>(xr + 28);

        float s0, c0, s1, c1, s2, c2, s3, c3;
        __sincosf(0.5f * xa.x, &s0, &c0);
        __sincosf(0.5f * xa.y, &s1, &c1);
        __sincosf(0.5f * xb.x, &s2, &c2);
        __sincosf(0.5f * xb.y, &s3, &c3);

        float t01[4] = {c0 * c1, c0 * s1, s0 * c1, s0 * s1};
        float t23[4] = {c2 * c3, c2 * s3, s2 * c3, s2 * s3};

        unsigned int pw[8];
#pragma unroll
        for (int q = 0; q < 8; ++q) {
            float plo = t01[(2 * q) >> 2]     * t23[(2 * q) & 3];
            float phv = t01[(2 * q + 1) >> 2] * t23[(2 * q + 1) & 3];
            pw[q] = pkbf(plo, phv);
        }
        *reinterpret_cast<uint4*>(&psiL[wv][lane][0]) =
            make_uint4(pw[0], pw[1], pw[2], pw[3]);
        *reinterpret_cast<uint4*>(&psiL[wv][lane][8]) =
            make_uint4(pw[4], pw[5], pw[6], pw[7]);
    }

    // ---- 4 sub-tiles of 16 items: U-MFMA -> square -> Z-MFMA -> store ----
#pragma unroll
    for (int sub = 0; sub < 4; ++sub) {
        int item16 = base + sub * 16 + lrow;
#if USE_X16
        bfrag4 Pf = *reinterpret_cast<const bfrag4*>(
            &psiL[wv][sub * 16 + lrow][lgrp * 4]);
        f32x4 dz = {0.f, 0.f, 0.f, 0.f};
        f32x4 d = __builtin_amdgcn_mfma_f32_16x16x16bf16_1k(Uf16, Pf, dz, 0, 0, 0);
        union { bfrag4 f; unsigned int u[2]; } qq;
        qq.u[0] = pkbf(d[0] * d[0], d[1] * d[1]);
        qq.u[1] = pkbf(d[2] * d[2], d[3] * d[3]);
        f32x4 m = __builtin_amdgcn_mfma_f32_16x16x16bf16_1k(Zf, qq.f, dz, 0, 0, 0);
        if (lgrp == 0) {
            int b16 = item16 / NPATCH;
            int p16 = item16 - b16 * NPATCH;
            uint2 o2;
            o2.x = pkbf(m[0], m[1]);   // w0, w1
            o2.y = pkbf(m[2], m[3]);   // w2, w3
            *reinterpret_cast<uint2*>(featsB + (size_t)b16 * KPAD + p16 * 4) = o2;
        }
#else
        bfrag Bf = {};
        if (lgrp < 2)
            Bf = *reinterpret_cast<const bfrag*>(
                &psiL[wv][sub * 16 + lrow][lgrp * 8]);
        f32x4 dz = {0.f, 0.f, 0.f, 0.f};
        f32x4 d = __builtin_amdgcn_mfma_f32_16x16x32_bf16(Uf, Bf, dz, 0, 0, 0);
        float q0 = d[0] * d[0], q1 = d[1] * d[1];
        float q2 = d[2] * d[2], q3 = d[3] * d[3];
        float sAll = (q0 + q1) + (q2 + q3);
        float uu2  = (q0 + q1) - (q2 + q3);
        float vv2  = (q0 - q1) + (q2 - q3);
        float t    = __shfl_xor(sAll, 16);
        float Aa   = sAll + t;
        float Bb   = ((threadIdx.x & 16)) ? (t - sAll) : (sAll - t);
        t = __shfl_xor(Aa, 32);
        float mw0 = ((threadIdx.x & 32)) ? (t - Aa) : (Aa - t);
        float mw1 = Bb + __shfl_xor(Bb, 32);
        float u16 = uu2 + __shfl_xor(uu2, 16);
        float mw2 = u16 + __shfl_xor(u16, 32);
        float v16 = vv2 + __shfl_xor(vv2, 16);
        float mw3 = v16 + __shfl_xor(v16, 32);
        if (lgrp == 0) {
            int b16 = item16 / NPATCH;
            int p16 = item16 - b16 * NPATCH;
            ushort4 o;
            o.x = f2bf(mw0); o.y = f2bf(mw1);
            o.z = f2bf(mw2); o.w = f2bf(mw3);
            *reinterpret_cast<ushort4*>(featsB + (size_t)b16 * KPAD + p16 * 4) = o;
        }
#endif
    }
}

// ===========================================================================
// K2: tail = fc1 (MFMA) + fc2+relu + fc3 + head. Grid 512 x 512 (8 waves).
// launch_bounds(512,1): let the register allocator keep many K-loop loads in
// flight. Dual accumulators halve the MFMA dependency depth.
// ===========================================================================
__global__ __launch_bounds__(512, 1) void tail_kernel(
    const unsigned short* __restrict__ featsB,
    const unsigned short* __restrict__ w1B,
    const float* __restrict__ b1,
    const float* __restrict__ w2, const float* __restrict__ b2,
    const float* __restrict__ w3, const float* __restrict__ b3,
    float* __restrict__ out)
{
    __shared__ __align__(16) unsigned short featsL[16 * FLD2];  // 25856 B
    __shared__ __align__(16) float h1L[16 * H1LD];              //  8448 B
    __shared__ __align__(16) float h2L[16 * 84];                //  5376 B

    const int tid  = threadIdx.x;
    const int lane = tid & 63;
    const int wv   = tid >> 6;          // 0..7
    const int lrow = lane & 15;
    const int lgrp = lane >> 4;
    const int m0   = blockIdx.x * 16;

    // ---- stage 16 feats rows: coalesced 16B chunks, 1600 tasks ----
    for (int t = tid; t < 16 * 100; t += 512) {
        int row = t / 100;
        int c   = t - row * 100;
        uint4 v = *reinterpret_cast<const uint4*>(
            featsB + (size_t)(m0 + row) * KPAD + c * 8);
        *reinterpret_cast<uint4*>(&featsL[row * FLD2 + c * 8]) = v;
    }
    __syncthreads();

    // ---- fc1: wave wv -> cols [16wv, 16wv+16); dual-acc pipelined K-loop ----
    {
        const unsigned short* fA  = &featsL[lrow * FLD2 + lgrp * 8];
        const unsigned short* bp  =
            w1B + (size_t)(wv * 16 + lrow) * KPAD + lgrp * 8;

        f32x4 acc0 = {}, acc1 = {};
#pragma unroll
        for (int k0 = 0; k0 < 768; k0 += 64) {
            bfrag a0  = *reinterpret_cast<const bfrag*>(fA + k0);
            bfrag bb0 = *reinterpret_cast<const bfrag*>(bp + k0);
            bfrag a1  = *reinterpret_cast<const bfrag*>(fA + k0 + 32);
            bfrag bb1 = *reinterpret_cast<const bfrag*>(bp + k0 + 32);
            acc0 = __builtin_amdgcn_mfma_f32_16x16x32_bf16(a0, bb0, acc0, 0, 0, 0);
            acc1 = __builtin_amdgcn_mfma_f32_16x16x32_bf16(a1, bb1, acc1, 0, 0, 0);
        }
        {   // K tail: 768..800
            bfrag a0  = *reinterpret_cast<const bfrag*>(fA + 768);
            bfrag bb0 = *reinterpret_cast<const bfrag*>(bp + 768);
            acc0 = __builtin_amdgcn_mfma_f32_16x16x32_bf16(a0, bb0, acc0, 0, 0, 0);
        }
        f32x4 acc = acc0 + acc1;

        int col = wv * 16 + lrow;
        if (col < 120) {
            float bias = b1[col];
#pragma unroll
            for (int rr = 0; rr < 4; ++rr) {
                int row = lgrp * 4 + rr;   // 0..15, all real
                h1L[row * H1LD + col] = fmaxf(acc[rr] + bias, 0.f);
            }
        }
    }
    __syncthreads();

    // ---- fc2+relu: 16 x 84 -> 336 col-quad items ----
    for (int e = tid; e < 16 * 21; e += 512) {
        int r  = e / 21;
        int nq = e - r * 21;
        int n0 = nq * 4;
        float4 bias = *reinterpret_cast<const float4*>(b2 + n0);
        float accv[4] = {bias.x, bias.y, bias.z, bias.w};
#pragma unroll
        for (int kq = 0; kq < 30; ++kq) {
            float4 a = *reinterpret_cast<const float4*>(&h1L[r * H1LD + kq * 4]);
#pragma unroll
            for (int nn = 0; nn < 4; ++nn) {
                const float4 wvv = *reinterpret_cast<const float4*>(
                    w2 + (size_t)(n0 + nn) * 120 + kq * 4);
                accv[nn] = fmaf(a.x, wvv.x, accv[nn]);
                accv[nn] = fmaf(a.y, wvv.y, accv[nn]);
                accv[nn] = fmaf(a.z, wvv.z, accv[nn]);
                accv[nn] = fmaf(a.w, wvv.w, accv[nn]);
            }
        }
        float4 o;
        o.x = fmaxf(accv[0], 0.f);
        o.y = fmaxf(accv[1], 0.f);
        o.z = fmaxf(accv[2], 0.f);
        o.w = fmaxf(accv[3], 0.f);
        *reinterpret_cast<float4*>(&h2L[r * 84 + n0]) = o;
    }
    __syncthreads();

    // ---- fc3 + head, one thread per row ----
    if (tid < 16) {
        int r = tid;
        float acc = b3[0];
#pragma unroll
        for (int kq = 0; kq < 21; ++kq) {
            float4 a   = *reinterpret_cast<const float4*>(&h2L[r * 84 + kq * 4]);
            float4 wvv = *reinterpret_cast<const float4*>(w3 + kq * 4);
            acc = fmaf(a.x, wvv.x, acc);
            acc = fmaf(a.y, wvv.y, acc);
            acc = fmaf(a.z, wvv.z, acc);
            acc = fmaf(a.w, wvv.w, acc);
        }
        float ev = 0.5f * (1.0f + __sinf(acc));
        float pp = 1.0f / (1.0f + __expf(-ev));
        out[m0 + r]         = pp;
        out[BATCH + m0 + r] = 1.0f - pp;
    }
}

// ===========================================================================
extern "C" void kernel_launch(void* const* d_in, const int* in_sizes, int n_in,
                              void* d_out, int out_size, void* d_ws, size_t ws_size,
                              hipStream_t stream)
{
    (void)in_sizes; (void)n_in; (void)out_size; (void)ws_size;
    const float* x  = (const float*)d_in[0];
    const float* U  = (const float*)d_in[1];
    const float* w1 = (const float*)d_in[2];
    const float* b1 = (const float*)d_in[3];
    const float* w2 = (const float*)d_in[4];
    const float* b2 = (const float*)d_in[5];
    const float* w3 = (const float*)d_in[6];
    const float* b3 = (const float*)d_in[7];
    float* out = (float*)d_out;

    unsigned short* w1B    = (unsigned short*)d_ws;            // 205 KB
    unsigned short* featsB = w1B + (size_t)128 * KPAD;         // 13.1 MB

    w1prep_kernel<<<dim3((128 * KPAD + 255) / 256), dim3(256), 0, stream>>>(w1, w1B);
    qfilter_kernel<<<dim3(NCHUNKS / 4), dim3(256), 0, stream>>>(x, U, featsB);
    tail_kernel<<<dim3(BATCH / 16), dim3(512), 0, stream>>>(
        featsB, w1B, b1, w2, b2, w3, b3, out);
}

// Round 11
// 125.903 us; speedup vs baseline: 1.0932x; 1.0932x over previous
//
#include <hip/hip_runtime.h>
#include <hip/hip_bf16.h>
#include <math.h>

// ---------------------------------------------------------------------------
// HybridClassifier, split pipeline v2 (split-K fc1, LDS-staged head):
//   K0 w1prep: w1 -> bf16 [128][800] (zero-padded)
//   K1 qfilter: 1 wave = 64 (batch,patch) items, grid 6272x256, no barriers.
//   K2 fc1_split: grid (512 m-tiles x 5 k-slices), 256 thr; 16 rows x 128
//       cols per block, K=160 per slice; raw f32 partials -> hp[ks].
//   K3 head: grid 512, 256 thr; sum partials + bias + relu -> h1 LDS;
//       w2 staged in LDS; fc2 -> fc3 -> analytic head -> out.
// ---------------------------------------------------------------------------

#define BATCH   8192
#define NPATCH  196
#define KPAD    800
#define KSLICE  160     // 5 slices x 160 = 800
#define FLD3    168     // feats LDS row stride (halves) for fc1 slice tile
#define H1LD    132
#define NCHUNKS ((BATCH * NPATCH) / 64)   // 25088 exact

typedef __attribute__((ext_vector_type(8))) short bfrag;    // 8 bf16 (x32 MFMA)
typedef __attribute__((ext_vector_type(4))) short bfrag4;   // 4 bf16 (x16 MFMA)
typedef __attribute__((ext_vector_type(4))) float f32x4;

#if __has_builtin(__builtin_amdgcn_mfma_f32_16x16x16bf16_1k)
#define USE_X16 1
#else
#define USE_X16 0
#endif

static __device__ __forceinline__ unsigned short f2bf(float f) {
    __hip_bfloat16 h = __float2bfloat16(f);
    return __builtin_bit_cast(unsigned short, h);
}
static __device__ __forceinline__ unsigned int pkbf(float lo, float hi) {
    return ((unsigned int)f2bf(hi) << 16) | (unsigned int)f2bf(lo);
}

// ===========================================================================
// K0: w1 (fp32 [120][784]) -> bf16 [128][800], zero-padded.
// ===========================================================================
__global__ __launch_bounds__(256) void w1prep_kernel(
    const float* __restrict__ w1, unsigned short* __restrict__ w1B)
{
    int t = blockIdx.x * 256 + threadIdx.x;
    if (t >= 128 * KPAD) return;
    int n = t / KPAD;
    int k = t - n * KPAD;
    float v = (n < 120 && k < 784) ? w1[n * 784 + k] : 0.f;
    w1B[t] = f2bf(v);
}

// ===========================================================================
// K1: quantum filter. One chunk (64 items) per wave, no loops, no barriers.
// ===========================================================================
__global__ __launch_bounds__(256) void qfilter_kernel(
    const float* __restrict__ x, const float* __restrict__ U,
    unsigned short* __restrict__ featsB)
{
    __shared__ __align__(16) unsigned short psiL[4][64][16];   // 8192 B

    const int lane = threadIdx.x & 63;
    const int wv   = threadIdx.x >> 6;
    const int lrow = lane & 15;
    const int lgrp = lane >> 4;
    const int base = (blockIdx.x * 4 + wv) * 64;

#if USE_X16
    bfrag4 Uf16;
    {
        union { bfrag4 f; unsigned int u[2]; } uu;
        float4 a = *reinterpret_cast<const float4*>(U + lrow * 16 + lgrp * 4);
        uu.u[0] = pkbf(a.x, a.y);
        uu.u[1] = pkbf(a.z, a.w);
        Uf16 = uu.f;
    }
    bfrag4 Zf;
    {
        union { bfrag4 f; unsigned int u[2]; } zz;
        if (lrow < 4) {
            float z[4];
#pragma unroll
            for (int j = 0; j < 4; ++j) {
                int k = 4 * lgrp + j;
                z[j] = ((k >> (3 - lrow)) & 1) ? -1.f : 1.f;
            }
            zz.u[0] = pkbf(z[0], z[1]);
            zz.u[1] = pkbf(z[2], z[3]);
        } else {
            zz.u[0] = zz.u[1] = 0u;
        }
        Zf = zz.f;
    }
#else
    bfrag Uf;
    {
        union { bfrag f; unsigned int u[4]; } uu;
        if (lgrp < 2) {
            float4 a = *reinterpret_cast<const float4*>(U + lrow * 16 + lgrp * 8);
            float4 b = *reinterpret_cast<const float4*>(U + lrow * 16 + lgrp * 8 + 4);
            uu.u[0] = pkbf(a.x, a.y); uu.u[1] = pkbf(a.z, a.w);
            uu.u[2] = pkbf(b.x, b.y); uu.u[3] = pkbf(b.z, b.w);
        } else {
            uu.u[0] = uu.u[1] = uu.u[2] = uu.u[3] = 0u;
        }
        Uf = uu.f;
    }
#endif

    {
        int item = base + lane;
        int b  = item / NPATCH;
        int p  = item - b * NPATCH;
        int pr = p / 14;
        int pc = p - pr * 14;
        const float* xr = x + (size_t)b * 784 + pr * 56 + pc * 2;
        float2 xa = *reinterpret_cast<const float2*>(xr);
        float2 xb = *reinterpret_cast<const float2*>(xr + 28);

        float s0, c0, s1, c1, s2, c2, s3, c3;
        __sincosf(0.5f * xa.x, &s0, &c0);
        __sincosf(0.5f * xa.y, &s1, &c1);
        __sincosf(0.5f * xb.x, &s2, &c2);
        __sincosf(0.5f * xb.y, &s3, &c3);

        float t01[4] = {c0 * c1, c0 * s1, s0 * c1, s0 * s1};
        float t23[4] = {c2 * c3, c2 * s3, s2 * c3, s2 * s3};

        unsigned int pw[8];
#pragma unroll
        for (int q = 0; q < 8; ++q) {
            float plo = t01[(2 * q) >> 2]     * t23[(2 * q) & 3];
            float phv = t01[(2 * q + 1) >> 2] * t23[(2 * q + 1) & 3];
            pw[q] = pkbf(plo, phv);
        }
        *reinterpret_cast<uint4*>(&psiL[wv][lane][0]) =
            make_uint4(pw[0], pw[1], pw[2], pw[3]);
        *reinterpret_cast<uint4*>(&psiL[wv][lane][8]) =
            make_uint4(pw[4], pw[5], pw[6], pw[7]);
    }

#pragma unroll
    for (int sub = 0; sub < 4; ++sub) {
        int item16 = base + sub * 16 + lrow;
#if USE_X16
        bfrag4 Pf = *reinterpret_cast<const bfrag4*>(
            &psiL[wv][sub * 16 + lrow][lgrp * 4]);
        f32x4 dz = {0.f, 0.f, 0.f, 0.f};
        f32x4 d = __builtin_amdgcn_mfma_f32_16x16x16bf16_1k(Uf16, Pf, dz, 0, 0, 0);
        union { bfrag4 f; unsigned int u[2]; } qq;
        qq.u[0] = pkbf(d[0] * d[0], d[1] * d[1]);
        qq.u[1] = pkbf(d[2] * d[2], d[3] * d[3]);
        f32x4 m = __builtin_amdgcn_mfma_f32_16x16x16bf16_1k(Zf, qq.f, dz, 0, 0, 0);
        if (lgrp == 0) {
            int b16 = item16 / NPATCH;
            int p16 = item16 - b16 * NPATCH;
            uint2 o2;
            o2.x = pkbf(m[0], m[1]);   // w0, w1
            o2.y = pkbf(m[2], m[3]);   // w2, w3
            *reinterpret_cast<uint2*>(featsB + (size_t)b16 * KPAD + p16 * 4) = o2;
        }
#else
        bfrag Bf = {};
        if (lgrp < 2)
            Bf = *reinterpret_cast<const bfrag*>(
                &psiL[wv][sub * 16 + lrow][lgrp * 8]);
        f32x4 dz = {0.f, 0.f, 0.f, 0.f};
        f32x4 d = __builtin_amdgcn_mfma_f32_16x16x32_bf16(Uf, Bf, dz, 0, 0, 0);
        float q0 = d[0] * d[0], q1 = d[1] * d[1];
        float q2 = d[2] * d[2], q3 = d[3] * d[3];
        float sAll = (q0 + q1) + (q2 + q3);
        float uu2  = (q0 + q1) - (q2 + q3);
        float vv2  = (q0 - q1) + (q2 - q3);
        float t    = __shfl_xor(sAll, 16);
        float Aa   = sAll + t;
        float Bb   = ((threadIdx.x & 16)) ? (t - sAll) : (sAll - t);
        t = __shfl_xor(Aa, 32);
        float mw0 = ((threadIdx.x & 32)) ? (t - Aa) : (Aa - t);
        float mw1 = Bb + __shfl_xor(Bb, 32);
        float u16 = uu2 + __shfl_xor(uu2, 16);
        float mw2 = u16 + __shfl_xor(u16, 32);
        float v16 = vv2 + __shfl_xor(vv2, 16);
        float mw3 = v16 + __shfl_xor(v16, 32);
        if (lgrp == 0) {
            int b16 = item16 / NPATCH;
            int p16 = item16 - b16 * NPATCH;
            ushort4 o;
            o.x = f2bf(mw0); o.y = f2bf(mw1);
            o.z = f2bf(mw2); o.w = f2bf(mw3);
            *reinterpret_cast<ushort4*>(featsB + (size_t)b16 * KPAD + p16 * 4) = o;
        }
#endif
    }
}

// ===========================================================================
// K2: fc1 split-K. Grid (512, 5), 256 threads. Block (ms, ks): rows
// [16ms,16ms+16) x cols [0,128) x K [160ks, 160ks+160). Stage the 16x160
// feats slice in LDS (stride 168), 4 waves x 32 cols, 5 K-iters, raw f32
// partials (no bias) -> hp[ks]. Short chains + 2560 blocks = latency hidden.
// ===========================================================================
__global__ __launch_bounds__(256) void fc1_kernel(
    const unsigned short* __restrict__ featsB,
    const unsigned short* __restrict__ w1B,
    float* __restrict__ hp)
{
    __shared__ __align__(16) unsigned short featsL[16 * FLD3];  // 5376 B

    const int tid  = threadIdx.x;
    const int lane = tid & 63;
    const int wv   = tid >> 6;
    const int lrow = lane & 15;
    const int lgrp = lane >> 4;
    const int m0   = blockIdx.x * 16;
    const int ks   = blockIdx.y;
    const int kb   = ks * KSLICE;

    // stage 16 rows x 160 halfs (20 uint4/row), coalesced
    for (int t = tid; t < 320; t += 256) {
        int row = t / 20;
        int c   = t - row * 20;
        uint4 v = *reinterpret_cast<const uint4*>(
            featsB + (size_t)(m0 + row) * KPAD + kb + c * 8);
        *reinterpret_cast<uint4*>(&featsL[row * FLD3 + c * 8]) = v;
    }
    __syncthreads();

    const unsigned short* fA  = &featsL[lrow * FLD3 + lgrp * 8];
    const unsigned short* bp0 = w1B + (size_t)(wv * 32 + lrow) * KPAD + kb + lgrp * 8;
    const unsigned short* bp1 = bp0 + 16 * KPAD;

    f32x4 acc0 = {}, acc1 = {};
#pragma unroll
    for (int k0 = 0; k0 < KSLICE; k0 += 32) {
        bfrag a   = *reinterpret_cast<const bfrag*>(fA + k0);
        bfrag b0  = *reinterpret_cast<const bfrag*>(bp0 + k0);
        bfrag b1f = *reinterpret_cast<const bfrag*>(bp1 + k0);
        acc0 = __builtin_amdgcn_mfma_f32_16x16x32_bf16(a, b0, acc0, 0, 0, 0);
        acc1 = __builtin_amdgcn_mfma_f32_16x16x32_bf16(a, b1f, acc1, 0, 0, 0);
    }

    float* hps = hp + (size_t)ks * (BATCH * 128);
    f32x4 accs[2] = {acc0, acc1};
#pragma unroll
    for (int nj = 0; nj < 2; ++nj) {
        int col = wv * 32 + nj * 16 + lrow;
        if (col < 120) {
#pragma unroll
            for (int rr = 0; rr < 4; ++rr)
                hps[(size_t)(m0 + lgrp * 4 + rr) * 128 + col] = accs[nj][rr];
        }
    }
}

// ===========================================================================
// K3: head. Grid 512, 256 threads. Sum 5 hp partials + bias + relu -> h1L;
// w2 staged in LDS; fc2 from LDS; fc3 via LDS w3; analytic head -> out.
// ===========================================================================
__global__ __launch_bounds__(256) void head_kernel(
    const float* __restrict__ hp,
    const float* __restrict__ b1,
    const float* __restrict__ w2, const float* __restrict__ b2,
    const float* __restrict__ w3, const float* __restrict__ b3,
    float* __restrict__ out)
{
    __shared__ __align__(16) float h1L[16 * H1LD];   //  8448 B
    __shared__ __align__(16) float w2L[84 * 120];    // 40320 B
    __shared__ __align__(16) float h2L[16 * 84];     //  5376 B
    __shared__ __align__(16) float w3L[88];          //   352 B

    const int tid = threadIdx.x;
    const int m0  = blockIdx.x * 16;

    // stage w2 (2520 float4) and w3 (21 float4)
    for (int t = tid; t < 2520; t += 256) {
        *reinterpret_cast<float4*>(&w2L[t * 4]) =
            *reinterpret_cast<const float4*>(w2 + t * 4);
    }
    if (tid < 21) {
        *reinterpret_cast<float4*>(&w3L[tid * 4]) =
            *reinterpret_cast<const float4*>(w3 + tid * 4);
    }

    // sum 5 partials + bias + relu: 480 (row, col-quad) tasks
    for (int t = tid; t < 480; t += 256) {
        int r  = t / 30;
        int nq = t - r * 30;
        const float* p0 = hp + (size_t)(m0 + r) * 128 + nq * 4;
        float4 s  = *reinterpret_cast<const float4*>(p0);
        float4 s1 = *reinterpret_cast<const float4*>(p0 + 1 * BATCH * 128);
        float4 s2 = *reinterpret_cast<const float4*>(p0 + 2 * BATCH * 128);
        float4 s3 = *reinterpret_cast<const float4*>(p0 + 3 * BATCH * 128);
        float4 s4 = *reinterpret_cast<const float4*>(p0 + 4 * BATCH * 128);
        float4 bias = *reinterpret_cast<const float4*>(b1 + nq * 4);
        float4 o;
        o.x = fmaxf(s.x + s1.x + s2.x + s3.x + s4.x + bias.x, 0.f);
        o.y = fmaxf(s.y + s1.y + s2.y + s3.y + s4.y + bias.y, 0.f);
        o.z = fmaxf(s.z + s1.z + s2.z + s3.z + s4.z + bias.z, 0.f);
        o.w = fmaxf(s.w + s1.w + s2.w + s3.w + s4.w + bias.w, 0.f);
        *reinterpret_cast<float4*>(&h1L[r * H1LD + nq * 4]) = o;
    }
    __syncthreads();

    // fc2+relu from LDS: 16 x 84 -> 336 col-quad items
    for (int e = tid; e < 16 * 21; e += 256) {
        int r  = e / 21;
        int nq = e - r * 21;
        int n0 = nq * 4;
        float4 bias = *reinterpret_cast<const float4*>(b2 + n0);
        float accv[4] = {bias.x, bias.y, bias.z, bias.w};
#pragma unroll
        for (int kq = 0; kq < 30; ++kq) {
            float4 a = *reinterpret_cast<const float4*>(&h1L[r * H1LD + kq * 4]);
#pragma unroll
            for (int nn = 0; nn < 4; ++nn) {
                const float4 wvv = *reinterpret_cast<const float4*>(
                    &w2L[(n0 + nn) * 120 + kq * 4]);
                accv[nn] = fmaf(a.x, wvv.x, accv[nn]);
                accv[nn] = fmaf(a.y, wvv.y, accv[nn]);
                accv[nn] = fmaf(a.z, wvv.z, accv[nn]);
                accv[nn] = fmaf(a.w, wvv.w, accv[nn]);
            }
        }
        float4 o;
        o.x = fmaxf(accv[0], 0.f);
        o.y = fmaxf(accv[1], 0.f);
        o.z = fmaxf(accv[2], 0.f);
        o.w = fmaxf(accv[3], 0.f);
        *reinterpret_cast<float4*>(&h2L[r * 84 + n0]) = o;
    }
    __syncthreads();

    // fc3 + head, one thread per row (w3 from LDS)
    if (tid < 16) {
        int r = tid;
        float acc = b3[0];
#pragma unroll
        for (int kq = 0; kq < 21; ++kq) {
            float4 a   = *reinterpret_cast<const float4*>(&h2L[r * 84 + kq * 4]);
            float4 wvv = *reinterpret_cast<const float4*>(&w3L[kq * 4]);
            acc = fmaf(a.x, wvv.x, acc);
            acc = fmaf(a.y, wvv.y, acc);
            acc = fmaf(a.z, wvv.z, acc);
            acc = fmaf(a.w, wvv.w, acc);
        }
        float ev = 0.5f * (1.0f + __sinf(acc));
        float pp = 1.0f / (1.0f + __expf(-ev));
        out[m0 + r]         = pp;
        out[BATCH + m0 + r] = 1.0f - pp;
    }
}

// ===========================================================================
extern "C" void kernel_launch(void* const* d_in, const int* in_sizes, int n_in,
                              void* d_out, int out_size, void* d_ws, size_t ws_size,
                              hipStream_t stream)
{
    (void)in_sizes; (void)n_in; (void)out_size; (void)ws_size;
    const float* x  = (const float*)d_in[0];
    const float* U  = (const float*)d_in[1];
    const float* w1 = (const float*)d_in[2];
    const float* b1 = (const float*)d_in[3];
    const float* w2 = (const float*)d_in[4];
    const float* b2 = (const float*)d_in[5];
    const float* w3 = (const float*)d_in[6];
    const float* b3 = (const float*)d_in[7];
    float* out = (float*)d_out;

    unsigned short* w1B    = (unsigned short*)d_ws;            // 205 KB
    unsigned short* featsB = w1B + (size_t)128 * KPAD;         // 13.1 MB
    float*          hp     = (float*)(featsB + (size_t)BATCH * KPAD);  // 20.5 MB

    w1prep_kernel<<<dim3((128 * KPAD + 255) / 256), dim3(256), 0, stream>>>(w1, w1B);
    qfilter_kernel<<<dim3(NCHUNKS / 4), dim3(256), 0, stream>>>(x, U, featsB);
    fc1_kernel<<<dim3(BATCH / 16, 5), dim3(256), 0, stream>>>(featsB, w1B, hp);
    head_kernel<<<dim3(BATCH / 16), dim3(256), 0, stream>>>(
        hp, b1, w2, b2, w3, b3, out);
}